// Round 1
// baseline (2356.529 us; speedup 1.0000x reference)
//
#include <hip/hip_runtime.h>

// Problem constants
#define NF 384   // A_F dimension
#define NH 256   // A dimension
#define MM 128   // columns (M)
#define PP 128   // rows (P)
#define KSTEPS 48  // Markov terms; truncation ~0.5^48, need only ~2%

// Sections of the step kernel grid (256 threads/block):
//   blocks [0,192): PF_next = A_F * PF   (384x128 outputs)
//   blocks [192,320): PH_next = A * PH   (256x128 outputs)
//   blocks [320,384): E_k = C_F*PF - C*PH; Sm += E_k; S1 += |E_k|^2
#define SEC_A (NF*MM)            // 49152
#define SEC_AB (NF*MM + NH*MM)   // 81920
#define TOTAL_T (SEC_AB + PP*MM) // 98304 -> 384 blocks

__global__ __launch_bounds__(256)
void init_kernel(const float* __restrict__ BFr, const float* __restrict__ BFi,
                 const float* __restrict__ DFr, const float* __restrict__ DFi,
                 float2* __restrict__ PF, float2* __restrict__ PH,
                 float2* __restrict__ Sm, float* __restrict__ S1) {
    int t = blockIdx.x * 256 + threadIdx.x;
    if (t < NF * MM) PF[t] = make_float2(BFr[t], BFi[t]);
    if (t < NH * MM) {
        int n = t >> 7, m = t & 127;
        PH[t] = make_float2((n == m) ? 1.0f : 0.0f, 0.0f);
    }
    if (t < PP * MM) Sm[t] = make_float2(DFr[t], DFi[t]);
    if (t == 0) *S1 = 0.0f;
}

__global__ __launch_bounds__(256)
void step_kernel(const float* __restrict__ AFr, const float* __restrict__ AFi,
                 const float* __restrict__ Ar,  const float* __restrict__ Ai,
                 const float* __restrict__ CFr, const float* __restrict__ CFi,
                 const float* __restrict__ Cr,  const float* __restrict__ Ci,
                 const float2* __restrict__ PFc, const float2* __restrict__ PHc,
                 float2* __restrict__ PFn, float2* __restrict__ PHn,
                 float2* __restrict__ Sm, float* __restrict__ S1) {
    int t = blockIdx.x * 256 + threadIdx.x;
    if (t < SEC_A) {
        // PF_next[r][m] = sum_k A_F[r][k] * PF[k][m]
        int r = t >> 7, m = t & 127;
        const float* ar_ = AFr + r * NF;
        const float* ai_ = AFi + r * NF;
        float accr = 0.f, acci = 0.f;
        #pragma unroll 4
        for (int k = 0; k < NF; ++k) {
            float br = ar_[k], bi = ai_[k];
            float2 p = PFc[k * MM + m];
            accr += br * p.x - bi * p.y;
            acci += br * p.y + bi * p.x;
        }
        PFn[t] = make_float2(accr, acci);
    } else if (t < SEC_AB) {
        // PH_next[r][m] = sum_k A[r][k] * PH[k][m]
        int u = t - SEC_A;
        int r = u >> 7, m = u & 127;
        const float* ar_ = Ar + r * NH;
        const float* ai_ = Ai + r * NH;
        float accr = 0.f, acci = 0.f;
        #pragma unroll 4
        for (int k = 0; k < NH; ++k) {
            float br = ar_[k], bi = ai_[k];
            float2 p = PHc[k * MM + m];
            accr += br * p.x - bi * p.y;
            acci += br * p.y + bi * p.x;
        }
        PHn[u] = make_float2(accr, acci);
    } else {
        // E[p][m] = sum_k C_F[p][k]*PF[k][m] - sum_k C[p][k]*PH[k][m]
        int u = t - SEC_AB;
        int p = u >> 7, m = u & 127;
        float er = 0.f, ei = 0.f;
        {
            const float* cr_ = CFr + p * NF;
            const float* ci_ = CFi + p * NF;
            #pragma unroll 4
            for (int k = 0; k < NF; ++k) {
                float br = cr_[k], bi = ci_[k];
                float2 x = PFc[k * MM + m];
                er += br * x.x - bi * x.y;
                ei += br * x.y + bi * x.x;
            }
        }
        {
            const float* cr_ = Cr + p * NH;
            const float* ci_ = Ci + p * NH;
            #pragma unroll 4
            for (int k = 0; k < NH; ++k) {
                float br = cr_[k], bi = ci_[k];
                float2 x = PHc[k * MM + m];
                er -= br * x.x - bi * x.y;
                ei -= br * x.y + bi * x.x;
            }
        }
        float2 s = Sm[u];
        Sm[u] = make_float2(s.x + er, s.y + ei);

        // block-reduce |E|^2 -> one atomic per block
        __shared__ float red[256];
        float v = er * er + ei * ei;
        red[threadIdx.x] = v;
        __syncthreads();
        for (int off = 128; off > 0; off >>= 1) {
            if (threadIdx.x < off) red[threadIdx.x] += red[threadIdx.x + off];
            __syncthreads();
        }
        if (threadIdx.x == 0) atomicAdd(S1, red[0]);
    }
}

__global__ __launch_bounds__(256)
void final_kernel(const float2* __restrict__ Sm, const float* __restrict__ S1,
                  const float* __restrict__ DFr, const float* __restrict__ DFi,
                  float* __restrict__ out) {
    __shared__ float red[256];
    float acc2 = 0.f, accD = 0.f;
    for (int i = threadIdx.x; i < PP * MM; i += 256) {
        float2 s = Sm[i];
        acc2 += s.x * s.x + s.y * s.y;
        float dr = DFr[i], di = DFi[i];
        accD += dr * dr + di * di;
    }
    red[threadIdx.x] = acc2;
    __syncthreads();
    for (int off = 128; off > 0; off >>= 1) {
        if (threadIdx.x < off) red[threadIdx.x] += red[threadIdx.x + off];
        __syncthreads();
    }
    float S2 = red[0];
    __syncthreads();
    red[threadIdx.x] = accD;
    __syncthreads();
    for (int off = 128; off > 0; off >>= 1) {
        if (threadIdx.x < off) red[threadIdx.x] += red[threadIdx.x + off];
        __syncthreads();
    }
    if (threadIdx.x == 0) {
        float SD = red[0];
        out[0] = (99.0f * (*S1 + SD) + S2) / 100.0f;
    }
}

extern "C" void kernel_launch(void* const* d_in, const int* in_sizes, int n_in,
                              void* d_out, int out_size, void* d_ws, size_t ws_size,
                              hipStream_t stream) {
    (void)in_sizes; (void)n_in; (void)out_size; (void)ws_size;
    const float* Cr  = (const float*)d_in[0];
    const float* Ci  = (const float*)d_in[1];
    const float* Ar  = (const float*)d_in[2];
    const float* Ai  = (const float*)d_in[3];
    const float* AFr = (const float*)d_in[4];
    const float* AFi = (const float*)d_in[5];
    const float* BFr = (const float*)d_in[6];
    const float* BFi = (const float*)d_in[7];
    const float* CFr = (const float*)d_in[8];
    const float* CFi = (const float*)d_in[9];
    const float* DFr = (const float*)d_in[10];
    const float* DFi = (const float*)d_in[11];
    float* out = (float*)d_out;

    // Workspace layout (bytes)
    char* ws = (char*)d_ws;
    float2* PF0 = (float2*)(ws);                         // 384*128*8 = 393216
    float2* PF1 = (float2*)(ws + 393216);                // 393216
    float2* PH0 = (float2*)(ws + 786432);                // 256*128*8 = 262144
    float2* PH1 = (float2*)(ws + 1048576);               // 262144
    float2* Sm  = (float2*)(ws + 1310720);               // 128*128*8 = 131072
    float*  S1  = (float*) (ws + 1441792);               // 4

    init_kernel<<<192, 256, 0, stream>>>(BFr, BFi, DFr, DFi, PF0, PH0, Sm, S1);

    float2* pfc = PF0; float2* pfn = PF1;
    float2* phc = PH0; float2* phn = PH1;
    for (int k = 0; k < KSTEPS; ++k) {
        step_kernel<<<TOTAL_T / 256, 256, 0, stream>>>(
            AFr, AFi, Ar, Ai, CFr, CFi, Cr, Ci,
            pfc, phc, pfn, phn, Sm, S1);
        float2* tf = pfc; pfc = pfn; pfn = tf;
        float2* th = phc; phc = phn; phn = th;
    }

    final_kernel<<<1, 256, 0, stream>>>(Sm, S1, DFr, DFi, out);
}

// Round 2
// 620.013 us; speedup vs baseline: 3.8008x; 3.8008x over previous
//
#include <hip/hip_runtime.h>

// Objective via Parseval over the 99th roots of unity (z=1 double-counted):
//   obj = (99*sum_t ||c_t||^2 + ||sum_t c_t||^2) / 100
// with c_0 = D_F, c_{k+1} = E_k = C_F A_F^k B_F - C A^k B.
// Iterate Q_F = C_F A_F^k (128x384), Q_H = C A^k (128x256):
//   E_k = Q_F B_F - Q_H[:, :128]   (B = eye(256,128))
// Step = two GEMMs: Q_F x [A_F | B_F] (k=384, out 128x512) and Q_H x A (k=256).
// K=24 terms: energy ratio <=~0.7/step => tail ~1e5 << 1e6 threshold.

#define KSTEPS 24
#define KC 32

__global__ __launch_bounds__(256)
void init_kernel(const float* __restrict__ Cr,  const float* __restrict__ Ci,
                 const float* __restrict__ CFr, const float* __restrict__ CFi,
                 const float* __restrict__ DFr, const float* __restrict__ DFi,
                 float2* __restrict__ QF, float2* __restrict__ QH,
                 float2* __restrict__ Sm, float* __restrict__ S1) {
    int t = blockIdx.x * 256 + threadIdx.x;
    if (t < 128 * 384) QF[t] = make_float2(CFr[t], CFi[t]);
    if (t < 128 * 256) QH[t] = make_float2(Cr[t], Ci[t]);
    if (t < 128 * 128) Sm[t] = make_float2(DFr[t], DFi[t]);
    if (t == 0) *S1 = 0.0f;
}

// Grid: 384 blocks of 256 threads.
//  b in [0,256): F-side. rp=b>>2, strip=b&3. Rows 2rp..2rp+1 of the 128x512
//     output [Q_F*A_F | Q_F*B_F]; strip 3 is the E-part (cols of B_F).
//  b in [256,384): H-side. rp=(b-256)>>1, strip=(b-256)&1. Q_H*A.
__global__ __launch_bounds__(256)
void step_kernel(const float* __restrict__ AFr, const float* __restrict__ AFi,
                 const float* __restrict__ Ar,  const float* __restrict__ Ai,
                 const float* __restrict__ BFr, const float* __restrict__ BFi,
                 const float2* __restrict__ QFc, const float2* __restrict__ QHc,
                 float2* __restrict__ QFn, float2* __restrict__ QHn,
                 float2* __restrict__ Sm, float* __restrict__ S1) {
    __shared__ float sBr[2][KC][128];
    __shared__ float sBi[2][KC][128];
    __shared__ float sQr[2][384];
    __shared__ float sQi[2][384];
    __shared__ float red[256];

    const int b = blockIdx.x, tid = threadIdx.x;
    const int row = tid >> 7;      // 0..1 : which output row of the pair
    const int mm  = tid & 127;     // 0..127: column within strip

    int p0, c0, kdepth, W, Wn;
    bool isE = false;
    const float *Brp, *Bip;
    const float2 *Qc;
    float2 *Qn;
    if (b < 256) {
        int rp = b >> 2, strip = b & 3;
        p0 = rp << 1; kdepth = 384; Qc = QFc; Qn = QFn; Wn = 384;
        if (strip < 3) { c0 = strip << 7; W = 384; Brp = AFr; Bip = AFi; }
        else           { c0 = 0;          W = 128; Brp = BFr; Bip = BFi; isE = true; }
    } else {
        int u = b - 256; int rp = u >> 1, strip = u & 1;
        p0 = rp << 1; kdepth = 256; W = 256; c0 = strip << 7;
        Brp = Ar; Bip = Ai; Qc = QHc; Qn = QHn; Wn = 256;
    }

    // Stage this block's two Q rows into LDS (read later as wave-uniform b128).
    for (int idx = tid; idx < 2 * kdepth; idx += 256) {
        int r = (idx >= kdepth) ? 1 : 0;
        int k = idx - (r ? kdepth : 0);
        float2 q = Qc[(p0 + r) * kdepth + k];
        sQr[r][k] = q.x; sQi[r][k] = q.y;
    }

    // Double-buffered chunk staging: global -> regs (prefetch) -> LDS (commit).
    float rBr[16], rBi[16];
    {   // prefetch + commit chunk 0
        #pragma unroll
        for (int j = 0; j < 16; ++j) {
            int g = (2 * j + row) * W + c0 + mm;
            rBr[j] = Brp[g];
            rBi[j] = Bip[g];
        }
        #pragma unroll
        for (int j = 0; j < 16; ++j) {
            sBr[0][2 * j + row][mm] = rBr[j];
            sBi[0][2 * j + row][mm] = rBi[j];
        }
    }
    __syncthreads();

    float accr = 0.f, acci = 0.f;
    const int nchunk = kdepth / KC;
    for (int ch = 0; ch < nchunk; ++ch) {
        if (ch + 1 < nchunk) {           // issue next chunk's global loads early
            int kc1 = (ch + 1) * KC;
            #pragma unroll
            for (int j = 0; j < 16; ++j) {
                int g = (kc1 + 2 * j + row) * W + c0 + mm;
                rBr[j] = Brp[g];
                rBi[j] = Bip[g];
            }
        }
        const int buf = ch & 1;
        const int kc = ch * KC;
        #pragma unroll
        for (int k4 = 0; k4 < KC; k4 += 4) {
            float4 qr = *(const float4*)&sQr[row][kc + k4];
            float4 qi = *(const float4*)&sQi[row][kc + k4];
            float br0 = sBr[buf][k4 + 0][mm], bi0 = sBi[buf][k4 + 0][mm];
            float br1 = sBr[buf][k4 + 1][mm], bi1 = sBi[buf][k4 + 1][mm];
            float br2 = sBr[buf][k4 + 2][mm], bi2 = sBi[buf][k4 + 2][mm];
            float br3 = sBr[buf][k4 + 3][mm], bi3 = sBi[buf][k4 + 3][mm];
            accr += qr.x * br0 - qi.x * bi0;  acci += qr.x * bi0 + qi.x * br0;
            accr += qr.y * br1 - qi.y * bi1;  acci += qr.y * bi1 + qi.y * br1;
            accr += qr.z * br2 - qi.z * bi2;  acci += qr.z * bi2 + qi.z * br2;
            accr += qr.w * br3 - qi.w * bi3;  acci += qr.w * bi3 + qi.w * br3;
        }
        if (ch + 1 < nchunk) {
            __syncthreads();
            const int nbuf = (ch + 1) & 1;
            #pragma unroll
            for (int j = 0; j < 16; ++j) {
                sBr[nbuf][2 * j + row][mm] = rBr[j];
                sBi[nbuf][2 * j + row][mm] = rBi[j];
            }
            __syncthreads();
        }
    }

    const int pout = p0 + row;
    if (!isE) {
        Qn[pout * Wn + c0 + mm] = make_float2(accr, acci);
    } else {
        // E = Q_F B_F - Q_H[:, :128]; accumulate Sm += E, S1 += |E|^2
        float2 qh = QHc[pout * 256 + mm];
        float er = accr - qh.x, ei = acci - qh.y;
        int so = pout * 128 + mm;
        float2 s = Sm[so];
        Sm[so] = make_float2(s.x + er, s.y + ei);
        red[tid] = er * er + ei * ei;
        __syncthreads();
        for (int off = 128; off > 0; off >>= 1) {
            if (tid < off) red[tid] += red[tid + off];
            __syncthreads();
        }
        if (tid == 0) atomicAdd(S1, red[0]);
    }
}

__global__ __launch_bounds__(256)
void final_kernel(const float2* __restrict__ Sm, const float* __restrict__ S1,
                  const float* __restrict__ DFr, const float* __restrict__ DFi,
                  float* __restrict__ out) {
    __shared__ float red[256];
    float acc2 = 0.f, accD = 0.f;
    for (int i = threadIdx.x; i < 128 * 128; i += 256) {
        float2 s = Sm[i];
        acc2 += s.x * s.x + s.y * s.y;
        float dr = DFr[i], di = DFi[i];
        accD += dr * dr + di * di;
    }
    red[threadIdx.x] = acc2;
    __syncthreads();
    for (int off = 128; off > 0; off >>= 1) {
        if (threadIdx.x < off) red[threadIdx.x] += red[threadIdx.x + off];
        __syncthreads();
    }
    float S2 = red[0];
    __syncthreads();
    red[threadIdx.x] = accD;
    __syncthreads();
    for (int off = 128; off > 0; off >>= 1) {
        if (threadIdx.x < off) red[threadIdx.x] += red[threadIdx.x + off];
        __syncthreads();
    }
    if (threadIdx.x == 0) {
        out[0] = (99.0f * (*S1 + red[0]) + S2) / 100.0f;
    }
}

extern "C" void kernel_launch(void* const* d_in, const int* in_sizes, int n_in,
                              void* d_out, int out_size, void* d_ws, size_t ws_size,
                              hipStream_t stream) {
    (void)in_sizes; (void)n_in; (void)out_size; (void)ws_size;
    const float* Cr  = (const float*)d_in[0];
    const float* Ci  = (const float*)d_in[1];
    const float* Ar  = (const float*)d_in[2];
    const float* Ai  = (const float*)d_in[3];
    const float* AFr = (const float*)d_in[4];
    const float* AFi = (const float*)d_in[5];
    const float* BFr = (const float*)d_in[6];
    const float* BFi = (const float*)d_in[7];
    const float* CFr = (const float*)d_in[8];
    const float* CFi = (const float*)d_in[9];
    const float* DFr = (const float*)d_in[10];
    const float* DFi = (const float*)d_in[11];
    float* out = (float*)d_out;

    char* ws = (char*)d_ws;
    float2* QF0 = (float2*)(ws);              // 128*384*8 = 393216
    float2* QF1 = (float2*)(ws + 393216);     // 393216
    float2* QH0 = (float2*)(ws + 786432);     // 128*256*8 = 262144
    float2* QH1 = (float2*)(ws + 1048576);    // 262144
    float2* Sm  = (float2*)(ws + 1310720);    // 128*128*8 = 131072
    float*  S1  = (float*) (ws + 1441792);    // 4

    init_kernel<<<192, 256, 0, stream>>>(Cr, Ci, CFr, CFi, DFr, DFi, QF0, QH0, Sm, S1);

    float2* qfc = QF0; float2* qfn = QF1;
    float2* qhc = QH0; float2* qhn = QH1;
    for (int k = 0; k < KSTEPS; ++k) {
        step_kernel<<<384, 256, 0, stream>>>(AFr, AFi, Ar, Ai, BFr, BFi,
                                             qfc, qhc, qfn, qhn, Sm, S1);
        float2* t0 = qfc; qfc = qfn; qfn = t0;
        float2* t1 = qhc; qhc = qhn; qhn = t1;
    }

    final_kernel<<<1, 256, 0, stream>>>(Sm, S1, DFr, DFi, out);
}

// Round 3
// 346.297 us; speedup vs baseline: 6.8049x; 1.7904x over previous
//
#include <hip/hip_runtime.h>

// obj = (99*sum_t ||c_t||^2 + ||sum_t c_t||^2)/100  (Parseval over 99th roots,
// z=1 double-counted), c_0 = D_F, c_{k+1} = E_k = C_F A_F^k B_F - C A^k B.
// Iterate Q_F = C_F A_F^k, Q_H = C A^k;  E_k = Q_F B_F - Q_H[:, :128].
// Step kernel: split-K GEMMs writing partials; next step sums partials while
// staging Q. E_{s-1} is finalized (Sm += E, S1 += |E|^2) by 8 extra blocks of
// step s. K=14: tail energy ~1e3 << 1e6 threshold.

#define KSTEPS 14
#define KC 16

__global__ __launch_bounds__(256)
void init_kernel(const float* __restrict__ DFr, const float* __restrict__ DFi,
                 float2* __restrict__ Sm, float* __restrict__ S1) {
    int t = blockIdx.x * 256 + threadIdx.x;
    if (t < 16384) Sm[t] = make_float2(DFr[t], DFi[t]);
    if (t == 0) *S1 = 0.0f;
}

__device__ __forceinline__ void finalize_E(int u, int tid,
                                           const float2* __restrict__ EFr,
                                           float2* __restrict__ Sm,
                                           float* __restrict__ S1,
                                           float* red) {
    float v = 0.f;
    #pragma unroll
    for (int j = 0; j < 8; ++j) {
        int i = u * 2048 + j * 256 + tid;
        float2 e0 = EFr[i], e1 = EFr[16384 + i], e2 = EFr[32768 + i], e3 = EFr[49152 + i];
        float er = e0.x + e1.x + e2.x + e3.x;
        float ei = e0.y + e1.y + e2.y + e3.y;
        float2 s = Sm[i];
        Sm[i] = make_float2(s.x + er, s.y + ei);
        v += er * er + ei * ei;
    }
    red[tid] = v;
    __syncthreads();
    for (int off = 128; off > 0; off >>= 1) {
        if (tid < off) red[tid] += red[tid + off];
        __syncthreads();
    }
    if (tid == 0) atomicAdd(S1, red[0]);
}

// Grid: 392 blocks x 256 threads.
//  [0,192):   F->A_F strips: rg=b/12 (8 rows), strip=(b%12)>>2 (128 cols), part=(b%12)&3 (k-chunk 96)
//  [192,256): F->B_F (E partials): rg=(b-192)>>2, part=(b-192)&3; part 0 subtracts Q_H[:, :128]
//  [256,384): H->A strips: rg=(b-256)>>3, strip, part (k-chunk 64)
//  [384,392): finalize E_{s-1} (skipped when first)
__global__ __launch_bounds__(256)
void step_kernel(const float* __restrict__ AFr, const float* __restrict__ AFi,
                 const float* __restrict__ Ar,  const float* __restrict__ Ai,
                 const float* __restrict__ BFr, const float* __restrict__ BFi,
                 const float* __restrict__ CFr, const float* __restrict__ CFi,
                 const float* __restrict__ Cr,  const float* __restrict__ Ci,
                 const float2* __restrict__ QFc, const float2* __restrict__ QHc,
                 float2* __restrict__ QFn, float2* __restrict__ QHn,
                 float2* __restrict__ EFw, const float2* __restrict__ EFr,
                 float2* __restrict__ Sm, float* __restrict__ S1, int first) {
    __shared__ float2 sB[2][KC][128];
    __shared__ float2 sQ[96][8];
    __shared__ float red[256];

    const int b = blockIdx.x, tid = threadIdx.x;

    if (b >= 384) {
        if (!first) finalize_E(b - 384, tid, EFr, Sm, S1, red);
        return;
    }

    int p0, c0, k0, kchunk, Wrow, qdepth, part;
    bool isE = false;
    const float *Br_, *Bi_, *Qr0, *Qi0;
    const float2 *Qpart;
    float2 *Optr;
    if (b < 192) {
        int rg = b / 12, rem = b % 12, strip = rem >> 2; part = rem & 3;
        p0 = rg * 8; c0 = strip * 128; k0 = part * 96; kchunk = 96; Wrow = 384; qdepth = 384;
        Br_ = AFr; Bi_ = AFi; Qpart = QFc; Qr0 = CFr; Qi0 = CFi;
        Optr = QFn + part * 49152;
    } else if (b < 256) {
        int u = b - 192, rg = u >> 2; part = u & 3;
        p0 = rg * 8; c0 = 0; k0 = part * 96; kchunk = 96; Wrow = 128; qdepth = 384;
        Br_ = BFr; Bi_ = BFi; Qpart = QFc; Qr0 = CFr; Qi0 = CFi;
        Optr = EFw + part * 16384; isE = true;
    } else {
        int u = b - 256, rg = u >> 3, rem = u & 7, strip = rem >> 2; part = rem & 3;
        p0 = rg * 8; c0 = strip * 128; k0 = part * 64; kchunk = 64; Wrow = 256; qdepth = 256;
        Br_ = Ar; Bi_ = Ai; Qpart = QHc; Qr0 = Cr; Qi0 = Ci;
        Optr = QHn + part * 32768;
    }
    const int qpartsz = 128 * qdepth;

    // Stage Q rows p0..p0+7 over k-range [k0, k0+kchunk) into sQ[k][row].
    for (int idx = tid; idx < 8 * kchunk; idx += 256) {
        int pr = idx / kchunk, kk = idx - pr * kchunk;
        int g = (p0 + pr) * qdepth + k0 + kk;
        float qr, qi;
        if (first) { qr = Qr0[g]; qi = Qi0[g]; }
        else {
            float2 a0 = Qpart[g], a1 = Qpart[qpartsz + g];
            float2 a2 = Qpart[2 * qpartsz + g], a3 = Qpart[3 * qpartsz + g];
            qr = a0.x + a1.x + a2.x + a3.x;
            qi = a0.y + a1.y + a2.y + a3.y;
        }
        sQ[kk][pr] = make_float2(qr, qi);
    }

    const int r = tid >> 6, c = tid & 63;          // 2x2 tile: rows p0+2r..+1, cols c0+2c..+1
    const int bcol = tid & 127, bk = tid >> 7;     // B staging coords

    float pbr[8], pbi[8];
    auto loadB = [&](int ch) {
        int kbase = k0 + ch * KC;
        #pragma unroll
        for (int j = 0; j < 8; ++j) {
            int g = (kbase + bk + 2 * j) * Wrow + c0 + bcol;
            pbr[j] = Br_[g]; pbi[j] = Bi_[g];
        }
    };
    auto commitB = [&](int buf) {
        #pragma unroll
        for (int j = 0; j < 8; ++j)
            sB[buf][bk + 2 * j][bcol] = make_float2(pbr[j], pbi[j]);
    };

    loadB(0);
    commitB(0);
    __syncthreads();

    float a00r = 0, a00i = 0, a01r = 0, a01i = 0;
    float a10r = 0, a10i = 0, a11r = 0, a11i = 0;
    const int nch = kchunk / KC;
    for (int ch = 0; ch < nch; ++ch) {
        if (ch > 0) { commitB(ch & 1); __syncthreads(); }
        if (ch + 1 < nch) loadB(ch + 1);   // issue next chunk's global loads early
        const int buf = ch & 1, kb = ch * KC;
        #pragma unroll
        for (int kk = 0; kk < KC; ++kk) {
            float4 qv = *(const float4*)&sQ[kb + kk][2 * r];
            float4 bv = *(const float4*)&sB[buf][kk][2 * c];
            a00r += qv.x * bv.x - qv.y * bv.y;  a00i += qv.x * bv.y + qv.y * bv.x;
            a01r += qv.x * bv.z - qv.y * bv.w;  a01i += qv.x * bv.w + qv.y * bv.z;
            a10r += qv.z * bv.x - qv.w * bv.y;  a10i += qv.z * bv.y + qv.w * bv.x;
            a11r += qv.z * bv.z - qv.w * bv.w;  a11i += qv.z * bv.w + qv.w * bv.z;
        }
    }

    const int prow = p0 + 2 * r, pcol = c0 + 2 * c;
    if (isE && part == 0) {
        // subtract Q_H[:, :128] once (folded into partial 0)
        int m0 = 2 * c;
        if (first) {
            a00r -= Cr[prow * 256 + m0];           a00i -= Ci[prow * 256 + m0];
            a01r -= Cr[prow * 256 + m0 + 1];       a01i -= Ci[prow * 256 + m0 + 1];
            a10r -= Cr[(prow + 1) * 256 + m0];     a10i -= Ci[(prow + 1) * 256 + m0];
            a11r -= Cr[(prow + 1) * 256 + m0 + 1]; a11i -= Ci[(prow + 1) * 256 + m0 + 1];
        } else {
            #pragma unroll
            for (int pt = 0; pt < 4; ++pt) {
                const float2* qh = QHc + pt * 32768;
                float2 v00 = qh[prow * 256 + m0],       v01 = qh[prow * 256 + m0 + 1];
                float2 v10 = qh[(prow + 1) * 256 + m0], v11 = qh[(prow + 1) * 256 + m0 + 1];
                a00r -= v00.x; a00i -= v00.y;  a01r -= v01.x; a01i -= v01.y;
                a10r -= v10.x; a10i -= v10.y;  a11r -= v11.x; a11i -= v11.y;
            }
        }
    }
    float4 st0 = make_float4(a00r, a00i, a01r, a01i);
    float4 st1 = make_float4(a10r, a10i, a11r, a11i);
    *(float4*)&Optr[prow * Wrow + pcol] = st0;
    *(float4*)&Optr[(prow + 1) * Wrow + pcol] = st1;
}

__global__ __launch_bounds__(256)
void finalize_kernel(const float2* __restrict__ EFr, float2* __restrict__ Sm,
                     float* __restrict__ S1) {
    __shared__ float red[256];
    finalize_E(blockIdx.x, threadIdx.x, EFr, Sm, S1, red);
}

__global__ __launch_bounds__(1024)
void final_kernel(const float2* __restrict__ Sm, const float* __restrict__ S1,
                  const float* __restrict__ DFr, const float* __restrict__ DFi,
                  float* __restrict__ out) {
    __shared__ float red[1024];
    float acc2 = 0.f, accD = 0.f;
    for (int i = threadIdx.x; i < 16384; i += 1024) {
        float2 s = Sm[i];
        acc2 += s.x * s.x + s.y * s.y;
        float dr = DFr[i], di = DFi[i];
        accD += dr * dr + di * di;
    }
    red[threadIdx.x] = acc2;
    __syncthreads();
    for (int off = 512; off > 0; off >>= 1) {
        if (threadIdx.x < off) red[threadIdx.x] += red[threadIdx.x + off];
        __syncthreads();
    }
    float S2 = red[0];
    __syncthreads();
    red[threadIdx.x] = accD;
    __syncthreads();
    for (int off = 512; off > 0; off >>= 1) {
        if (threadIdx.x < off) red[threadIdx.x] += red[threadIdx.x + off];
        __syncthreads();
    }
    if (threadIdx.x == 0) out[0] = (99.0f * (*S1 + red[0]) + S2) / 100.0f;
}

extern "C" void kernel_launch(void* const* d_in, const int* in_sizes, int n_in,
                              void* d_out, int out_size, void* d_ws, size_t ws_size,
                              hipStream_t stream) {
    (void)in_sizes; (void)n_in; (void)out_size; (void)ws_size;
    const float* Cr  = (const float*)d_in[0];
    const float* Ci  = (const float*)d_in[1];
    const float* Ar  = (const float*)d_in[2];
    const float* Ai  = (const float*)d_in[3];
    const float* AFr = (const float*)d_in[4];
    const float* AFi = (const float*)d_in[5];
    const float* BFr = (const float*)d_in[6];
    const float* BFi = (const float*)d_in[7];
    const float* CFr = (const float*)d_in[8];
    const float* CFi = (const float*)d_in[9];
    const float* DFr = (const float*)d_in[10];
    const float* DFi = (const float*)d_in[11];
    float* out = (float*)d_out;

    char* ws = (char*)d_ws;
    float2* QF0 = (float2*)(ws);                    // 4*128*384 f2 = 1.57 MB
    float2* QF1 = (float2*)(ws + 1572864);
    float2* QH0 = (float2*)(ws + 3145728);          // 4*128*256 f2 = 1.05 MB
    float2* QH1 = (float2*)(ws + 4194304);
    float2* EF0 = (float2*)(ws + 5242880);          // 4*128*128 f2 = 0.52 MB
    float2* EF1 = (float2*)(ws + 5767168);
    float2* Sm  = (float2*)(ws + 6291456);          // 128*128 f2
    float*  S1  = (float*) (ws + 6422528);

    init_kernel<<<64, 256, 0, stream>>>(DFr, DFi, Sm, S1);

    float2 *qfc = QF0, *qfn = QF1, *qhc = QH0, *qhn = QH1, *efw = EF0, *efr = EF1;
    for (int s = 0; s < KSTEPS; ++s) {
        step_kernel<<<392, 256, 0, stream>>>(AFr, AFi, Ar, Ai, BFr, BFi,
                                             CFr, CFi, Cr, Ci,
                                             qfc, qhc, qfn, qhn, efw, efr,
                                             Sm, S1, (s == 0) ? 1 : 0);
        float2* t;
        t = qfc; qfc = qfn; qfn = t;
        t = qhc; qhc = qhn; qhn = t;
        t = efw; efw = efr; efr = t;
    }
    // after final swap, efr holds E_{KSTEPS-1} partials
    finalize_kernel<<<8, 256, 0, stream>>>(efr, Sm, S1);
    final_kernel<<<1, 1024, 0, stream>>>(Sm, S1, DFr, DFi, out);
}